// Round 11
// baseline (331.666 us; speedup 1.0000x reference)
//
#include <hip/hip_runtime.h>
#include <hip/hip_bf16.h>

constexpr int NB = 32768;    // batch
constexpr int NF = 256;      // features
constexpr int NM = 10;       // memory slots
constexpr float DECAY = 0.9f;

using bf16x8 = __attribute__((ext_vector_type(8))) short;
using f32x4  = __attribute__((ext_vector_type(4))) float;

static __device__ __forceinline__ ushort f2bf(float x) {
    unsigned u = __float_as_uint(x);
    unsigned r = (u + 0x7fffu + ((u >> 16) & 1u)) >> 16;
    return (ushort)r;
}
static __device__ __forceinline__ float bf2f(ushort x) {
    return __uint_as_float(((unsigned)x) << 16);
}
static __device__ __forceinline__ float sigmoid_f(float x) {
    return 1.f / (1.f + __expf(-x));
}
static __device__ __forceinline__ float tanh_f(float x) {
    float e = __expf(2.f * x);
    return (e - 1.f) / (e + 1.f);
}
static __device__ __forceinline__ void gload16(const void* g, void* l) {
    __builtin_amdgcn_global_load_lds(
        (const __attribute__((address_space(1))) unsigned int*)g,
        (__attribute__((address_space(3))) unsigned int*)l, 16, 0, 0);
}
static __device__ __forceinline__ int swzb(int row, int byteInRow) {
    return (row * 512 + byteInRow) ^ ((row & 7) << 4);
}

// ---------------- fused weight/input prep (one launch) ----------------
constexpr int PB_ACAT = 16384;
constexpr int PB_WGI  = PB_ACAT + 1024;
constexpr int PB_WQKT = PB_WGI + 256;
constexpr int PB_WV   = PB_WQKT + 256;
constexpr int PB_TOT  = PB_WV + 1;

__global__ __launch_bounds__(256) void k_prep(
    const float* __restrict__ W_ih, const float* __restrict__ W_hh,
    const float* __restrict__ b_ih, const float* __restrict__ b_hh,
    const float* __restrict__ Wq, const float* __restrict__ bq,
    const float* __restrict__ Wk, const float* __restrict__ Wv,
    const float* __restrict__ nf, const float* __restrict__ hidden,
    const int* __restrict__ idx,
    ushort* __restrict__ Wg, float* __restrict__ bsum,
    ushort* __restrict__ WqkT, float* __restrict__ bqk,
    ushort* __restrict__ Wvb, ushort* __restrict__ Acat)
{
    const int blk = blockIdx.x, tid = threadIdx.x;
    if (blk < PB_ACAT) {
        int t = blk * 256 + tid;
        int row = t >> 7;
        int c4 = (t & 127) * 4;
        const float* src = (c4 < 256) ? (nf + (size_t)row * 256 + c4)
                                      : (hidden + (size_t)idx[row] * 256 + (c4 - 256));
        float4 v = *reinterpret_cast<const float4*>(src);
        ushort4 o;
        o.x = f2bf(v.x); o.y = f2bf(v.y); o.z = f2bf(v.z); o.w = f2bf(v.w);
        *reinterpret_cast<ushort4*>(Acat + (size_t)row * 512 + c4) = o;
    } else if (blk < PB_WGI) {
        int j = blk - PB_ACAT;
        for (int c = tid; c < 512; c += 256) {
            float v = (c < 256) ? W_ih[j * 256 + c] : W_hh[j * 256 + (c - 256)];
            Wg[j * 512 + c] = f2bf(v);
        }
        if (tid == 0) bsum[j] = b_ih[j] + b_hh[j];
    } else if (blk < PB_WQKT) {
        int i = blk - PB_WGI, a = tid;
        float s = 0.f;
#pragma unroll 8
        for (int j = 0; j < 256; ++j) s += Wq[j * 256 + a] * Wk[j * 256 + i];
        WqkT[i * 256 + a] = f2bf(s * 0.0625f);
    } else if (blk < PB_WV) {
        int t = (blk - PB_WQKT) * 256 + tid;
        Wvb[t] = f2bf(Wv[t]);
    } else {
        int i = tid;
        float s = 0.f;
#pragma unroll 8
        for (int j = 0; j < 256; ++j) s += bq[j] * Wk[j * 256 + i];
        bqk[i] = s * 0.0625f;
    }
}

// ---------------- gates GEMM (r9 form: gate-planar + XCD-cohort) ----------------
__global__ __launch_bounds__(256) void k_gates2(
    const ushort* __restrict__ Acat, const ushort* __restrict__ Wg,
    const float* __restrict__ bsum, const int* __restrict__ idx,
    const float* __restrict__ cell, ushort* __restrict__ h_new)
{
    __shared__ ushort As[128 * 32];
    __shared__ ushort Bs[128 * 32];
    const int t = threadIdx.x;
    const int w = t >> 6, l = t & 63;
    const int wr = w >> 1, wc = w & 1;
    const int lr = l & 15, lk = l >> 4;

    const int flat = blockIdx.x;
    const int xc = flat & 7, grp = flat >> 3;
    const int by = grp & 7;
    const int bx = (grp >> 3) * 8 + xc;
    const int row0 = bx * 128;
    const int f0 = by * 32;

    f32x4 acc[4][4];
#pragma unroll
    for (int m = 0; m < 4; ++m)
#pragma unroll
        for (int g = 0; g < 4; ++g) acc[m][g] = f32x4{0.f, 0.f, 0.f, 0.f};

    const int srow = l >> 2;
    const int scol = (l & 3) * 8;
    const int u0 = w * 2, u1 = u0 + 1;
    const ushort* aS0 = Acat + (size_t)(row0 + u0 * 16 + srow) * 512 + scol;
    const ushort* aS1 = Acat + (size_t)(row0 + u1 * 16 + srow) * 512 + scol;
    const ushort* bS0 = Wg + (size_t)(w * 256 + f0 + srow) * 512 + scol;
    const ushort* bS1 = Wg + (size_t)(w * 256 + f0 + 16 + srow) * 512 + scol;
    ushort* aL0 = As + u0 * 512; ushort* aL1 = As + u1 * 512;
    ushort* bL0 = Bs + (w * 32) * 32; ushort* bL1 = Bs + (w * 32 + 16) * 32;

    for (int k0 = 0; k0 < 512; k0 += 32) {
        gload16(aS0 + k0, aL0);
        gload16(aS1 + k0, aL1);
        gload16(bS0 + k0, bL0);
        gload16(bS1 + k0, bL1);
        __syncthreads();
        bf16x8 af[4], bfr[4];
#pragma unroll
        for (int m = 0; m < 4; ++m)
            af[m] = *reinterpret_cast<const bf16x8*>(As + (wr * 64 + m * 16 + lr) * 32 + lk * 8);
#pragma unroll
        for (int g = 0; g < 4; ++g)
            bfr[g] = *reinterpret_cast<const bf16x8*>(Bs + (g * 32 + wc * 16 + lr) * 32 + lk * 8);
#pragma unroll
        for (int m = 0; m < 4; ++m)
#pragma unroll
            for (int g = 0; g < 4; ++g)
                acc[m][g] = __builtin_amdgcn_mfma_f32_16x16x32_bf16(af[m], bfr[g], acc[m][g], 0, 0, 0);
        __syncthreads();
    }

    const int f = f0 + wc * 16 + lr;
    float bs[4];
#pragma unroll
    for (int g = 0; g < 4; ++g) bs[g] = bsum[g * 256 + f];

    int nodev[4][4];
#pragma unroll
    for (int m = 0; m < 4; ++m)
#pragma unroll
        for (int r = 0; r < 4; ++r)
            nodev[m][r] = idx[row0 + wr * 64 + m * 16 + lk * 4 + r];

#pragma unroll
    for (int m = 0; m < 4; ++m) {
#pragma unroll
        for (int r = 0; r < 4; ++r) {
            float gi = acc[m][0][r] + bs[0];
            float gf = acc[m][1][r] + bs[1];
            float gg = acc[m][2][r] + bs[2];
            float go = acc[m][3][r] + bs[3];
            float cp = cell[(size_t)nodev[m][r] * 256 + f];
            float cn = sigmoid_f(gf) * cp + sigmoid_f(gi) * tanh_f(gg);
            float hn = sigmoid_f(go) * tanh_f(cn);
            int row = row0 + wr * 64 + m * 16 + lk * 4 + r;
            h_new[(size_t)row * 256 + f] = f2bf(hn);
        }
    }
}

// ---------------- fused tail: q-GEMM -> pipelined attention -> out-GEMM ----------------
__global__ __launch_bounds__(256) void k_attnout(
    const ushort* __restrict__ hnew, const ushort* __restrict__ WqkT,
    const float* __restrict__ bqk, const ushort* __restrict__ Wvb,
    const float* __restrict__ bv, const int* __restrict__ idx,
    const int* __restrict__ mptr, const float* __restrict__ tm,
    const float* __restrict__ nf, float* __restrict__ out)
{
    __shared__ ushort sC[16 * 256];
    char* sB = (char*)sC;
    const int t = threadIdx.x, w = t >> 6, l = t & 63;
    const int lr = l & 15, lk = l >> 4;
    const int row0 = blockIdx.x * 16;

    {
        f32x4 qa[4];
#pragma unroll
        for (int n = 0; n < 4; ++n) qa[n] = f32x4{0.f, 0.f, 0.f, 0.f};
        const ushort* ap = hnew + (size_t)(row0 + lr) * 256 + lk * 8;
        const ushort* bp[4];
#pragma unroll
        for (int n = 0; n < 4; ++n) bp[n] = WqkT + (size_t)(w * 64 + n * 16 + lr) * 256 + lk * 8;
#pragma unroll 2
        for (int k0 = 0; k0 < 256; k0 += 32) {
            bf16x8 a = *reinterpret_cast<const bf16x8*>(ap + k0);
            bf16x8 b[4];
#pragma unroll
            for (int n = 0; n < 4; ++n) b[n] = *reinterpret_cast<const bf16x8*>(bp[n] + k0);
#pragma unroll
            for (int n = 0; n < 4; ++n)
                qa[n] = __builtin_amdgcn_mfma_f32_16x16x32_bf16(a, b[n], qa[n], 0, 0, 0);
        }
#pragma unroll
        for (int n = 0; n < 4; ++n) {
            int colc = w * 64 + n * 16 + lr;
            float bbq = bqk[colc];
#pragma unroll
            for (int r = 0; r < 4; ++r) {
                int row = lk * 4 + r;
                *(ushort*)(sB + swzb(row, colc * 2)) = f2bf(qa[n][r] + bbq);
            }
        }
    }
    __syncthreads();

    {
        const int b0 = row0 + w * 4;
        int nodes[4], ptrs[4];
#pragma unroll
        for (int r = 0; r < 4; ++r) { nodes[r] = idx[b0 + r]; ptrs[r] = mptr[nodes[r]]; }

        float4 mA[NM], mB[NM];

        auto loadRow = [&](float4* mm, int rr) {
            const int b = b0 + rr;
            const int node = nodes[rr], ptr = ptrs[rr];
            const float* base = tm + (size_t)node * (NM * NF);
            const float* nfp = nf + (size_t)b * 256 + l * 4;
#pragma unroll
            for (int m = 0; m < NM; ++m) {
                mm[m] = (m == ptr) ? *reinterpret_cast<const float4*>(nfp)
                                   : *reinterpret_cast<const float4*>(base + (size_t)m * 256 + l * 4);
            }
        };
        auto compRow = [&](float4* mm, int rr) {
            const int row = w * 4 + rr;
            const int ptr = ptrs[rr];
            ushort4 q4 = *(const ushort4*)(sB + swzb(row, l * 8));
            float q0 = bf2f(q4.x), q1 = bf2f(q4.y), q2 = bf2f(q4.z), q3 = bf2f(q4.w);
            float sc[NM];
#pragma unroll
            for (int m = 0; m < NM; ++m) {
                float4 v = mm[m];
                if (ptr > 0 && m == ptr - 1) { v.x *= DECAY; v.y *= DECAY; v.z *= DECAY; v.w *= DECAY; mm[m] = v; }
                sc[m] = q0 * v.x + q1 * v.y + q2 * v.z + q3 * v.w;
            }
#pragma unroll
            for (int m = 0; m < NM; ++m) {
                float s = sc[m];
#pragma unroll
                for (int d = 1; d < 64; d <<= 1) s += __shfl_xor(s, d, 64);
                sc[m] = s;
            }
            float mx = sc[0];
#pragma unroll
            for (int m = 1; m < NM; ++m) mx = fmaxf(mx, sc[m]);
            float e[NM], sum = 0.f;
#pragma unroll
            for (int m = 0; m < NM; ++m) { e[m] = __expf(sc[m] - mx); sum += e[m]; }
            float inv = 1.f / sum;
            float4 c = {0.f, 0.f, 0.f, 0.f};
#pragma unroll
            for (int m = 0; m < NM; ++m) {
                float wm = e[m] * inv;
                c.x += wm * mm[m].x; c.y += wm * mm[m].y; c.z += wm * mm[m].z; c.w += wm * mm[m].w;
            }
            ushort4 o;
            o.x = f2bf(c.x); o.y = f2bf(c.y); o.z = f2bf(c.z); o.w = f2bf(c.w);
            *(ushort4*)(sB + swzb(row, l * 8)) = o;
        };

        loadRow(mA, 0);
        loadRow(mB, 1);
        compRow(mA, 0);
        loadRow(mA, 2);
        compRow(mB, 1);
        loadRow(mB, 3);
        compRow(mA, 2);
        compRow(mB, 3);
    }
    __syncthreads();

    f32x4 acc[4];
#pragma unroll
    for (int n = 0; n < 4; ++n) acc[n] = f32x4{0.f, 0.f, 0.f, 0.f};
    const ushort* vptr[4];
#pragma unroll
    for (int n = 0; n < 4; ++n) vptr[n] = Wvb + (size_t)(w * 64 + n * 16 + lr) * 256 + lk * 8;

#pragma unroll 2
    for (int k = 0; k < 256; k += 32) {
        bf16x8 a = *reinterpret_cast<const bf16x8*>(sB + swzb(lr, (k + lk * 8) * 2));
        bf16x8 b[4];
#pragma unroll
        for (int n = 0; n < 4; ++n) b[n] = *reinterpret_cast<const bf16x8*>(vptr[n] + k);
#pragma unroll
        for (int n = 0; n < 4; ++n)
            acc[n] = __builtin_amdgcn_mfma_f32_16x16x32_bf16(a, b[n], acc[n], 0, 0, 0);
    }
#pragma unroll
    for (int n = 0; n < 4; ++n) {
        int colc = w * 64 + n * 16 + lr;
        float bbv = bv[colc];
#pragma unroll
        for (int r = 0; r < 4; ++r) {
            int row = lk * 4 + r;
            out[(size_t)(row0 + row) * 256 + colc] = acc[n][r] + bbv;
        }
    }
}

// ---------------- launch ----------------
// MEASUREMENT ROUND: k_attnout is idempotent (reads hnew/tm/nf/weights only,
// writes d_out with identical values) -> launched TWICE.
// dur11 - dur10 = A'(fused attnout) + gap. Everything else identical to r10.
extern "C" void kernel_launch(void* const* d_in, const int* in_sizes, int n_in,
                              void* d_out, int out_size, void* d_ws, size_t ws_size,
                              hipStream_t stream) {
    const int*   node_indices = (const int*)  d_in[0];
    const float* node_feats   = (const float*)d_in[1];
    const float* hidden       = (const float*)d_in[2];
    const float* cell         = (const float*)d_in[3];
    const float* tmem         = (const float*)d_in[4];
    const int*   memory_ptr   = (const int*)  d_in[5];
    const float* W_ih         = (const float*)d_in[6];
    const float* W_hh         = (const float*)d_in[7];
    const float* b_ih         = (const float*)d_in[8];
    const float* b_hh         = (const float*)d_in[9];
    const float* Wq           = (const float*)d_in[10];
    const float* bq           = (const float*)d_in[11];
    const float* Wk           = (const float*)d_in[12];
    // d_in[13] = bk: softmax-invariant, unused
    const float* Wv           = (const float*)d_in[14];
    const float* bv           = (const float*)d_in[15];

    char* ws = (char*)d_ws;
    size_t off = 0;
    auto alloc = [&](size_t bytes) { char* p = ws + off; off += (bytes + 255) & ~(size_t)255; return p; };

    ushort* Wg    = (ushort*)alloc((size_t)1024 * 512 * 2);
    ushort* WqkT  = (ushort*)alloc((size_t)256 * 256 * 2);
    ushort* Wvb   = (ushort*)alloc((size_t)256 * 256 * 2);
    float*  bqk   = (float*) alloc((size_t)256 * 4);
    float*  bsum  = (float*) alloc((size_t)1024 * 4);
    ushort* Acat  = (ushort*)alloc((size_t)NB * 512 * 2);
    ushort* hnew  = (ushort*)alloc((size_t)NB * 256 * 2);

    k_prep<<<PB_TOT, 256, 0, stream>>>(W_ih, W_hh, b_ih, b_hh, Wq, bq, Wk, Wv,
                                       node_feats, hidden, node_indices,
                                       Wg, bsum, WqkT, bqk, Wvb, Acat);
    k_gates2<<<2048, 256, 0, stream>>>(Acat, Wg, bsum, node_indices, cell, hnew);
    k_attnout<<<NB / 16, 256, 0, stream>>>(hnew, WqkT, bqk, Wvb, bv, node_indices,
                                           memory_ptr, tmem, node_feats, (float*)d_out);
    k_attnout<<<NB / 16, 256, 0, stream>>>(hnew, WqkT, bqk, Wvb, bv, node_indices,
                                           memory_ptr, tmem, node_feats, (float*)d_out);
}

// Round 12
// 219.665 us; speedup vs baseline: 1.5099x; 1.5099x over previous
//
#include <hip/hip_runtime.h>
#include <hip/hip_bf16.h>

constexpr int NB = 32768;    // batch
constexpr int NF = 256;      // features
constexpr int NM = 10;       // memory slots
constexpr float DECAY = 0.9f;

using bf16x8 = __attribute__((ext_vector_type(8))) short;
using f32x4  = __attribute__((ext_vector_type(4))) float;

static __device__ __forceinline__ ushort f2bf(float x) {
    unsigned u = __float_as_uint(x);
    unsigned r = (u + 0x7fffu + ((u >> 16) & 1u)) >> 16;
    return (ushort)r;
}
static __device__ __forceinline__ float bf2f(ushort x) {
    return __uint_as_float(((unsigned)x) << 16);
}
static __device__ __forceinline__ float sigmoid_f(float x) {
    return 1.f / (1.f + __expf(-x));
}
static __device__ __forceinline__ float tanh_f(float x) {
    float e = __expf(2.f * x);
    return (e - 1.f) / (e + 1.f);
}
static __device__ __forceinline__ void gload16(const void* g, void* l) {
    __builtin_amdgcn_global_load_lds(
        (const __attribute__((address_space(1))) unsigned int*)g,
        (__attribute__((address_space(3))) unsigned int*)l, 16, 0, 0);
}
static __device__ __forceinline__ int swzb(int row, int byteInRow) {
    return (row * 512 + byteInRow) ^ ((row & 7) << 4);
}

// ---------------- fused weight/input prep (one launch) ----------------
constexpr int PB_ACAT = 16384;
constexpr int PB_WGI  = PB_ACAT + 1024;
constexpr int PB_WQKT = PB_WGI + 256;
constexpr int PB_WV   = PB_WQKT + 256;
constexpr int PB_TOT  = PB_WV + 1;

__global__ __launch_bounds__(256) void k_prep(
    const float* __restrict__ W_ih, const float* __restrict__ W_hh,
    const float* __restrict__ b_ih, const float* __restrict__ b_hh,
    const float* __restrict__ Wq, const float* __restrict__ bq,
    const float* __restrict__ Wk, const float* __restrict__ Wv,
    const float* __restrict__ nf, const float* __restrict__ hidden,
    const int* __restrict__ idx,
    ushort* __restrict__ Wg, float* __restrict__ bsum,
    ushort* __restrict__ WqkT, float* __restrict__ bqk,
    ushort* __restrict__ Wvb, ushort* __restrict__ Acat)
{
    const int blk = blockIdx.x, tid = threadIdx.x;
    if (blk < PB_ACAT) {
        int t = blk * 256 + tid;
        int row = t >> 7;
        int c4 = (t & 127) * 4;
        const float* src = (c4 < 256) ? (nf + (size_t)row * 256 + c4)
                                      : (hidden + (size_t)idx[row] * 256 + (c4 - 256));
        float4 v = *reinterpret_cast<const float4*>(src);
        ushort4 o;
        o.x = f2bf(v.x); o.y = f2bf(v.y); o.z = f2bf(v.z); o.w = f2bf(v.w);
        *reinterpret_cast<ushort4*>(Acat + (size_t)row * 512 + c4) = o;
    } else if (blk < PB_WGI) {
        int j = blk - PB_ACAT;
        for (int c = tid; c < 512; c += 256) {
            float v = (c < 256) ? W_ih[j * 256 + c] : W_hh[j * 256 + (c - 256)];
            Wg[j * 512 + c] = f2bf(v);
        }
        if (tid == 0) bsum[j] = b_ih[j] + b_hh[j];
    } else if (blk < PB_WQKT) {
        int i = blk - PB_WGI, a = tid;
        float s = 0.f;
#pragma unroll 8
        for (int j = 0; j < 256; ++j) s += Wq[j * 256 + a] * Wk[j * 256 + i];
        WqkT[i * 256 + a] = f2bf(s * 0.0625f);
    } else if (blk < PB_WV) {
        int t = (blk - PB_WQKT) * 256 + tid;
        Wvb[t] = f2bf(Wv[t]);
    } else {
        int i = tid;
        float s = 0.f;
#pragma unroll 8
        for (int j = 0; j < 256; ++j) s += bq[j] * Wk[j * 256 + i];
        bqk[i] = s * 0.0625f;
    }
}

// ---------------- gates GEMM (gate-planar + XCD-cohort, r9 form) ----------------
__global__ __launch_bounds__(256) void k_gates2(
    const ushort* __restrict__ Acat, const ushort* __restrict__ Wg,
    const float* __restrict__ bsum, const int* __restrict__ idx,
    const float* __restrict__ cell, ushort* __restrict__ h_new)
{
    __shared__ ushort As[128 * 32];
    __shared__ ushort Bs[128 * 32];
    const int t = threadIdx.x;
    const int w = t >> 6, l = t & 63;
    const int wr = w >> 1, wc = w & 1;
    const int lr = l & 15, lk = l >> 4;

    const int flat = blockIdx.x;
    const int xc = flat & 7, grp = flat >> 3;
    const int by = grp & 7;
    const int bx = (grp >> 3) * 8 + xc;
    const int row0 = bx * 128;
    const int f0 = by * 32;

    f32x4 acc[4][4];
#pragma unroll
    for (int m = 0; m < 4; ++m)
#pragma unroll
        for (int g = 0; g < 4; ++g) acc[m][g] = f32x4{0.f, 0.f, 0.f, 0.f};

    const int srow = l >> 2;
    const int scol = (l & 3) * 8;
    const int u0 = w * 2, u1 = u0 + 1;
    const ushort* aS0 = Acat + (size_t)(row0 + u0 * 16 + srow) * 512 + scol;
    const ushort* aS1 = Acat + (size_t)(row0 + u1 * 16 + srow) * 512 + scol;
    const ushort* bS0 = Wg + (size_t)(w * 256 + f0 + srow) * 512 + scol;
    const ushort* bS1 = Wg + (size_t)(w * 256 + f0 + 16 + srow) * 512 + scol;
    ushort* aL0 = As + u0 * 512; ushort* aL1 = As + u1 * 512;
    ushort* bL0 = Bs + (w * 32) * 32; ushort* bL1 = Bs + (w * 32 + 16) * 32;

    for (int k0 = 0; k0 < 512; k0 += 32) {
        gload16(aS0 + k0, aL0);
        gload16(aS1 + k0, aL1);
        gload16(bS0 + k0, bL0);
        gload16(bS1 + k0, bL1);
        __syncthreads();
        bf16x8 af[4], bfr[4];
#pragma unroll
        for (int m = 0; m < 4; ++m)
            af[m] = *reinterpret_cast<const bf16x8*>(As + (wr * 64 + m * 16 + lr) * 32 + lk * 8);
#pragma unroll
        for (int g = 0; g < 4; ++g)
            bfr[g] = *reinterpret_cast<const bf16x8*>(Bs + (g * 32 + wc * 16 + lr) * 32 + lk * 8);
#pragma unroll
        for (int m = 0; m < 4; ++m)
#pragma unroll
            for (int g = 0; g < 4; ++g)
                acc[m][g] = __builtin_amdgcn_mfma_f32_16x16x32_bf16(af[m], bfr[g], acc[m][g], 0, 0, 0);
        __syncthreads();
    }

    const int f = f0 + wc * 16 + lr;
    float bs[4];
#pragma unroll
    for (int g = 0; g < 4; ++g) bs[g] = bsum[g * 256 + f];

    int nodev[4][4];
#pragma unroll
    for (int m = 0; m < 4; ++m)
#pragma unroll
        for (int r = 0; r < 4; ++r)
            nodev[m][r] = idx[row0 + wr * 64 + m * 16 + lk * 4 + r];

#pragma unroll
    for (int m = 0; m < 4; ++m) {
#pragma unroll
        for (int r = 0; r < 4; ++r) {
            float gi = acc[m][0][r] + bs[0];
            float gf = acc[m][1][r] + bs[1];
            float gg = acc[m][2][r] + bs[2];
            float go = acc[m][3][r] + bs[3];
            float cp = cell[(size_t)nodev[m][r] * 256 + f];
            float cn = sigmoid_f(gf) * cp + sigmoid_f(gi) * tanh_f(gg);
            float hn = sigmoid_f(go) * tanh_f(cn);
            int row = row0 + wr * 64 + m * 16 + lk * 4 + r;
            h_new[(size_t)row * 256 + f] = f2bf(hn);
        }
    }
}

// ---------------- fused tail: q-GEMM -> attention -> out-GEMM ----------------
// 16 rows/block, grid 2048. No row pipeline (r10 null, costs VGPR); setprio on MFMA.
__global__ __launch_bounds__(256) void k_attnout(
    const ushort* __restrict__ hnew, const ushort* __restrict__ WqkT,
    const float* __restrict__ bqk, const ushort* __restrict__ Wvb,
    const float* __restrict__ bv, const int* __restrict__ idx,
    const int* __restrict__ mptr, const float* __restrict__ tm,
    const float* __restrict__ nf, float* __restrict__ out)
{
    __shared__ ushort sC[16 * 256];     // 8 KB; q rows, then (in-place) ctx rows
    char* sB = (char*)sC;
    const int t = threadIdx.x, w = t >> 6, l = t & 63;
    const int lr = l & 15, lk = l >> 4;
    const int row0 = blockIdx.x * 16;

    // ---- phase A: q = hnew[16x256] @ WqkT^T + bqk -> LDS (swizzled bf16) ----
    {
        f32x4 qa[4];
#pragma unroll
        for (int n = 0; n < 4; ++n) qa[n] = f32x4{0.f, 0.f, 0.f, 0.f};
        const ushort* ap = hnew + (size_t)(row0 + lr) * 256 + lk * 8;
        const ushort* bp[4];
#pragma unroll
        for (int n = 0; n < 4; ++n) bp[n] = WqkT + (size_t)(w * 64 + n * 16 + lr) * 256 + lk * 8;
        __builtin_amdgcn_s_setprio(1);
#pragma unroll 2
        for (int k0 = 0; k0 < 256; k0 += 32) {
            bf16x8 a = *reinterpret_cast<const bf16x8*>(ap + k0);
            bf16x8 b[4];
#pragma unroll
            for (int n = 0; n < 4; ++n) b[n] = *reinterpret_cast<const bf16x8*>(bp[n] + k0);
#pragma unroll
            for (int n = 0; n < 4; ++n)
                qa[n] = __builtin_amdgcn_mfma_f32_16x16x32_bf16(a, b[n], qa[n], 0, 0, 0);
        }
        __builtin_amdgcn_s_setprio(0);
#pragma unroll
        for (int n = 0; n < 4; ++n) {
            int colc = w * 64 + n * 16 + lr;
            float bbq = bqk[colc];
#pragma unroll
            for (int r = 0; r < 4; ++r) {
                int row = lk * 4 + r;
                *(ushort*)(sB + swzb(row, colc * 2)) = f2bf(qa[n][r] + bbq);
            }
        }
    }
    __syncthreads();

    // ---- phase B: attention; wave w owns rows [w*4, w*4+4) ----
    {
        const int b0 = row0 + w * 4;
        int nodes[4], ptrs[4];
#pragma unroll
        for (int r = 0; r < 4; ++r) { nodes[r] = idx[b0 + r]; ptrs[r] = mptr[nodes[r]]; }

        for (int rr = 0; rr < 4; ++rr) {
            const int row = w * 4 + rr;
            const int b = b0 + rr;
            const int node = nodes[rr];
            const int ptr = ptrs[rr];
            ushort4 q4 = *(const ushort4*)(sB + swzb(row, l * 8));
            float q0 = bf2f(q4.x), q1 = bf2f(q4.y), q2 = bf2f(q4.z), q3 = bf2f(q4.w);
            const float* base = tm + (size_t)node * (NM * NF);
            const float* nfp = nf + (size_t)b * 256 + l * 4;

            float4 mem[NM];
            float sc[NM];
#pragma unroll
            for (int m = 0; m < NM; ++m) {
                float4 v = (m == ptr) ? *reinterpret_cast<const float4*>(nfp)
                                      : *reinterpret_cast<const float4*>(base + (size_t)m * 256 + l * 4);
                if (ptr > 0 && m == ptr - 1) { v.x *= DECAY; v.y *= DECAY; v.z *= DECAY; v.w *= DECAY; }
                mem[m] = v;
                sc[m] = q0 * v.x + q1 * v.y + q2 * v.z + q3 * v.w;
            }
#pragma unroll
            for (int m = 0; m < NM; ++m) {
                float s = sc[m];
#pragma unroll
                for (int d = 1; d < 64; d <<= 1) s += __shfl_xor(s, d, 64);
                sc[m] = s;
            }
            float mx = sc[0];
#pragma unroll
            for (int m = 1; m < NM; ++m) mx = fmaxf(mx, sc[m]);
            float e[NM], sum = 0.f;
#pragma unroll
            for (int m = 0; m < NM; ++m) { e[m] = __expf(sc[m] - mx); sum += e[m]; }
            float inv = 1.f / sum;
            float4 c = {0.f, 0.f, 0.f, 0.f};
#pragma unroll
            for (int m = 0; m < NM; ++m) {
                float wm = e[m] * inv;
                c.x += wm * mem[m].x; c.y += wm * mem[m].y; c.z += wm * mem[m].z; c.w += wm * mem[m].w;
            }
            ushort4 o;
            o.x = f2bf(c.x); o.y = f2bf(c.y); o.z = f2bf(c.z); o.w = f2bf(c.w);
            *(ushort4*)(sB + swzb(row, l * 8)) = o;
        }
    }
    __syncthreads();

    // ---- phase C: out = ctx @ Wv^T + bv ----
    f32x4 acc[4];
#pragma unroll
    for (int n = 0; n < 4; ++n) acc[n] = f32x4{0.f, 0.f, 0.f, 0.f};
    const ushort* vptr[4];
#pragma unroll
    for (int n = 0; n < 4; ++n) vptr[n] = Wvb + (size_t)(w * 64 + n * 16 + lr) * 256 + lk * 8;

    __builtin_amdgcn_s_setprio(1);
#pragma unroll 2
    for (int k = 0; k < 256; k += 32) {
        bf16x8 a = *reinterpret_cast<const bf16x8*>(sB + swzb(lr, (k + lk * 8) * 2));
        bf16x8 b[4];
#pragma unroll
        for (int n = 0; n < 4; ++n) b[n] = *reinterpret_cast<const bf16x8*>(vptr[n] + k);
#pragma unroll
        for (int n = 0; n < 4; ++n)
            acc[n] = __builtin_amdgcn_mfma_f32_16x16x32_bf16(a, b[n], acc[n], 0, 0, 0);
    }
    __builtin_amdgcn_s_setprio(0);
#pragma unroll
    for (int n = 0; n < 4; ++n) {
        int colc = w * 64 + n * 16 + lr;
        float bbv = bv[colc];
#pragma unroll
        for (int r = 0; r < 4; ++r) {
            int row = lk * 4 + r;
            out[(size_t)(row0 + row) * 256 + colc] = acc[n][r] + bbv;
        }
    }
}

// ---------------- launch ----------------
extern "C" void kernel_launch(void* const* d_in, const int* in_sizes, int n_in,
                              void* d_out, int out_size, void* d_ws, size_t ws_size,
                              hipStream_t stream) {
    const int*   node_indices = (const int*)  d_in[0];
    const float* node_feats   = (const float*)d_in[1];
    const float* hidden       = (const float*)d_in[2];
    const float* cell         = (const float*)d_in[3];
    const float* tmem         = (const float*)d_in[4];
    const int*   memory_ptr   = (const int*)  d_in[5];
    const float* W_ih         = (const float*)d_in[6];
    const float* W_hh         = (const float*)d_in[7];
    const float* b_ih         = (const float*)d_in[8];
    const float* b_hh         = (const float*)d_in[9];
    const float* Wq           = (const float*)d_in[10];
    const float* bq           = (const float*)d_in[11];
    const float* Wk           = (const float*)d_in[12];
    // d_in[13] = bk: softmax-invariant, unused
    const float* Wv           = (const float*)d_in[14];
    const float* bv           = (const float*)d_in[15];

    char* ws = (char*)d_ws;
    size_t off = 0;
    auto alloc = [&](size_t bytes) { char* p = ws + off; off += (bytes + 255) & ~(size_t)255; return p; };

    ushort* Wg    = (ushort*)alloc((size_t)1024 * 512 * 2);
    ushort* WqkT  = (ushort*)alloc((size_t)256 * 256 * 2);
    ushort* Wvb   = (ushort*)alloc((size_t)256 * 256 * 2);
    float*  bqk   = (float*) alloc((size_t)256 * 4);
    float*  bsum  = (float*) alloc((size_t)1024 * 4);
    ushort* Acat  = (ushort*)alloc((size_t)NB * 512 * 2);
    ushort* hnew  = (ushort*)alloc((size_t)NB * 256 * 2);

    k_prep<<<PB_TOT, 256, 0, stream>>>(W_ih, W_hh, b_ih, b_hh, Wq, bq, Wk, Wv,
                                       node_feats, hidden, node_indices,
                                       Wg, bsum, WqkT, bqk, Wvb, Acat);
    k_gates2<<<2048, 256, 0, stream>>>(Acat, Wg, bsum, node_indices, cell, hnew);
    k_attnout<<<NB / 16, 256, 0, stream>>>(hnew, WqkT, bqk, Wvb, bv, node_indices,
                                           memory_ptr, tmem, node_feats, (float*)d_out);
}

// Round 13
// 207.659 us; speedup vs baseline: 1.5972x; 1.0578x over previous
//
#include <hip/hip_runtime.h>
#include <hip/hip_bf16.h>

constexpr int NB = 32768;    // batch
constexpr int NF = 256;      // features
constexpr int NM = 10;       // memory slots
constexpr float DECAY = 0.9f;

using bf16x8 = __attribute__((ext_vector_type(8))) short;
using f32x4  = __attribute__((ext_vector_type(4))) float;

static __device__ __forceinline__ ushort f2bf(float x) {
    unsigned u = __float_as_uint(x);
    unsigned r = (u + 0x7fffu + ((u >> 16) & 1u)) >> 16;
    return (ushort)r;
}
static __device__ __forceinline__ float bf2f(ushort x) {
    return __uint_as_float(((unsigned)x) << 16);
}
static __device__ __forceinline__ float sigmoid_f(float x) {
    return 1.f / (1.f + __expf(-x));
}
static __device__ __forceinline__ float tanh_f(float x) {
    float e = __expf(2.f * x);
    return (e - 1.f) / (e + 1.f);
}
static __device__ __forceinline__ void gload16(const void* g, void* l) {
    __builtin_amdgcn_global_load_lds(
        (const __attribute__((address_space(1))) unsigned int*)g,
        (__attribute__((address_space(3))) unsigned int*)l, 16, 0, 0);
}
static __device__ __forceinline__ int swzb(int row, int byteInRow) {
    return (row * 512 + byteInRow) ^ ((row & 7) << 4);
}

// ---------------- fused weight/input prep (one launch) ----------------
constexpr int PB_ACAT = 16384;
constexpr int PB_WGI  = PB_ACAT + 1024;
constexpr int PB_WQKT = PB_WGI + 256;
constexpr int PB_WV   = PB_WQKT + 256;
constexpr int PB_TOT  = PB_WV + 1;

__global__ __launch_bounds__(256) void k_prep(
    const float* __restrict__ W_ih, const float* __restrict__ W_hh,
    const float* __restrict__ b_ih, const float* __restrict__ b_hh,
    const float* __restrict__ Wq, const float* __restrict__ bq,
    const float* __restrict__ Wk, const float* __restrict__ Wv,
    const float* __restrict__ nf, const float* __restrict__ hidden,
    const int* __restrict__ idx,
    ushort* __restrict__ Wg, float* __restrict__ bsum,
    ushort* __restrict__ WqkT, float* __restrict__ bqk,
    ushort* __restrict__ Wvb, ushort* __restrict__ Acat)
{
    const int blk = blockIdx.x, tid = threadIdx.x;
    if (blk < PB_ACAT) {
        int t = blk * 256 + tid;
        int row = t >> 7;
        int c4 = (t & 127) * 4;
        const float* src = (c4 < 256) ? (nf + (size_t)row * 256 + c4)
                                      : (hidden + (size_t)idx[row] * 256 + (c4 - 256));
        float4 v = *reinterpret_cast<const float4*>(src);
        ushort4 o;
        o.x = f2bf(v.x); o.y = f2bf(v.y); o.z = f2bf(v.z); o.w = f2bf(v.w);
        *reinterpret_cast<ushort4*>(Acat + (size_t)row * 512 + c4) = o;
    } else if (blk < PB_WGI) {
        int j = blk - PB_ACAT;
        for (int c = tid; c < 512; c += 256) {
            float v = (c < 256) ? W_ih[j * 256 + c] : W_hh[j * 256 + (c - 256)];
            Wg[j * 512 + c] = f2bf(v);
        }
        if (tid == 0) bsum[j] = b_ih[j] + b_hh[j];
    } else if (blk < PB_WQKT) {
        int i = blk - PB_WGI, a = tid;
        float s = 0.f;
#pragma unroll 8
        for (int j = 0; j < 256; ++j) s += Wq[j * 256 + a] * Wk[j * 256 + i];
        WqkT[i * 256 + a] = f2bf(s * 0.0625f);
    } else if (blk < PB_WV) {
        int t = (blk - PB_WQKT) * 256 + tid;
        Wvb[t] = f2bf(Wv[t]);
    } else {
        int i = tid;
        float s = 0.f;
#pragma unroll 8
        for (int j = 0; j < 256; ++j) s += bq[j] * Wk[j * 256 + i];
        bqk[i] = s * 0.0625f;
    }
}

// ---------------- gates GEMM: BK=64 via two 32-wide sub-tiles, one barrier pair ----------------
// 8 K-iterations instead of 16 -> half the vmcnt(0)+barrier drains. Each sub-tile keeps
// the proven [*, 32] 64B-row-stride layout (no new bank conflicts, no swizzle needed).
__global__ __launch_bounds__(256) void k_gates2(
    const ushort* __restrict__ Acat, const ushort* __restrict__ Wg,
    const float* __restrict__ bsum, const int* __restrict__ idx,
    const float* __restrict__ cell, ushort* __restrict__ h_new)
{
    __shared__ ushort As[2][128 * 32];   // half h: K cols [k0+32h, k0+32h+32)
    __shared__ ushort Bs[2][128 * 32];
    const int t = threadIdx.x;
    const int w = t >> 6, l = t & 63;
    const int wr = w >> 1, wc = w & 1;
    const int lr = l & 15, lk = l >> 4;

    // XCD-cohort remap (8 feature-blocks of one row-block share an XCD's L2)
    const int flat = blockIdx.x;
    const int xc = flat & 7, grp = flat >> 3;
    const int by = grp & 7;
    const int bx = (grp >> 3) * 8 + xc;
    const int row0 = bx * 128;
    const int f0 = by * 32;

    f32x4 acc[4][4];                     // [m][gate]
#pragma unroll
    for (int m = 0; m < 4; ++m)
#pragma unroll
        for (int g = 0; g < 4; ++g) acc[m][g] = f32x4{0.f, 0.f, 0.f, 0.f};

    const int srow = l >> 2;
    const int scol = (l & 3) * 8;
    const int u0 = w * 2, u1 = u0 + 1;
    const ushort* aS0 = Acat + (size_t)(row0 + u0 * 16 + srow) * 512 + scol;
    const ushort* aS1 = Acat + (size_t)(row0 + u1 * 16 + srow) * 512 + scol;
    const ushort* bS0 = Wg + (size_t)(w * 256 + f0 + srow) * 512 + scol;
    const ushort* bS1 = Wg + (size_t)(w * 256 + f0 + 16 + srow) * 512 + scol;
    ushort* aL0_0 = As[0] + u0 * 512; ushort* aL1_0 = As[0] + u1 * 512;
    ushort* aL0_1 = As[1] + u0 * 512; ushort* aL1_1 = As[1] + u1 * 512;
    ushort* bL0_0 = Bs[0] + (w * 32) * 32; ushort* bL1_0 = Bs[0] + (w * 32 + 16) * 32;
    ushort* bL0_1 = Bs[1] + (w * 32) * 32; ushort* bL1_1 = Bs[1] + (w * 32 + 16) * 32;

    for (int k0 = 0; k0 < 512; k0 += 64) {
        // stage BOTH 32-wide halves, then one barrier
        gload16(aS0 + k0,      aL0_0);
        gload16(aS1 + k0,      aL1_0);
        gload16(aS0 + k0 + 32, aL0_1);
        gload16(aS1 + k0 + 32, aL1_1);
        gload16(bS0 + k0,      bL0_0);
        gload16(bS1 + k0,      bL1_0);
        gload16(bS0 + k0 + 32, bL0_1);
        gload16(bS1 + k0 + 32, bL1_1);
        __syncthreads();
#pragma unroll
        for (int h = 0; h < 2; ++h) {
            bf16x8 af[4], bfr[4];
#pragma unroll
            for (int m = 0; m < 4; ++m)
                af[m] = *reinterpret_cast<const bf16x8*>(As[h] + (wr * 64 + m * 16 + lr) * 32 + lk * 8);
#pragma unroll
            for (int g = 0; g < 4; ++g)
                bfr[g] = *reinterpret_cast<const bf16x8*>(Bs[h] + (g * 32 + wc * 16 + lr) * 32 + lk * 8);
#pragma unroll
            for (int m = 0; m < 4; ++m)
#pragma unroll
                for (int g = 0; g < 4; ++g)
                    acc[m][g] = __builtin_amdgcn_mfma_f32_16x16x32_bf16(af[m], bfr[g], acc[m][g], 0, 0, 0);
        }
        __syncthreads();
    }

    // ---- epilogue: per lane, feature f fixed; all 4 gates local ----
    const int f = f0 + wc * 16 + lr;
    float bs[4];
#pragma unroll
    for (int g = 0; g < 4; ++g) bs[g] = bsum[g * 256 + f];

    int nodev[4][4];
#pragma unroll
    for (int m = 0; m < 4; ++m)
#pragma unroll
        for (int r = 0; r < 4; ++r)
            nodev[m][r] = idx[row0 + wr * 64 + m * 16 + lk * 4 + r];

#pragma unroll
    for (int m = 0; m < 4; ++m) {
#pragma unroll
        for (int r = 0; r < 4; ++r) {
            float gi = acc[m][0][r] + bs[0];
            float gf = acc[m][1][r] + bs[1];
            float gg = acc[m][2][r] + bs[2];
            float go = acc[m][3][r] + bs[3];
            float cp = cell[(size_t)nodev[m][r] * 256 + f];
            float cn = sigmoid_f(gf) * cp + sigmoid_f(gi) * tanh_f(gg);
            float hn = sigmoid_f(go) * tanh_f(cn);
            int row = row0 + wr * 64 + m * 16 + lk * 4 + r;
            h_new[(size_t)row * 256 + f] = f2bf(hn);
        }
    }
}

// ---------------- fused tail: q-GEMM -> attention -> out-GEMM (r12 minus setprio) ----------------
__global__ __launch_bounds__(256) void k_attnout(
    const ushort* __restrict__ hnew, const ushort* __restrict__ WqkT,
    const float* __restrict__ bqk, const ushort* __restrict__ Wvb,
    const float* __restrict__ bv, const int* __restrict__ idx,
    const int* __restrict__ mptr, const float* __restrict__ tm,
    const float* __restrict__ nf, float* __restrict__ out)
{
    __shared__ ushort sC[16 * 256];     // 8 KB; q rows, then (in-place) ctx rows
    char* sB = (char*)sC;
    const int t = threadIdx.x, w = t >> 6, l = t & 63;
    const int lr = l & 15, lk = l >> 4;
    const int row0 = blockIdx.x * 16;

    // ---- phase A: q = hnew[16x256] @ WqkT^T + bqk -> LDS (swizzled bf16) ----
    {
        f32x4 qa[4];
#pragma unroll
        for (int n = 0; n < 4; ++n) qa[n] = f32x4{0.f, 0.f, 0.f, 0.f};
        const ushort* ap = hnew + (size_t)(row0 + lr) * 256 + lk * 8;
        const ushort* bp[4];
#pragma unroll
        for (int n = 0; n < 4; ++n) bp[n] = WqkT + (size_t)(w * 64 + n * 16 + lr) * 256 + lk * 8;
#pragma unroll 2
        for (int k0 = 0; k0 < 256; k0 += 32) {
            bf16x8 a = *reinterpret_cast<const bf16x8*>(ap + k0);
            bf16x8 b[4];
#pragma unroll
            for (int n = 0; n < 4; ++n) b[n] = *reinterpret_cast<const bf16x8*>(bp[n] + k0);
#pragma unroll
            for (int n = 0; n < 4; ++n)
                qa[n] = __builtin_amdgcn_mfma_f32_16x16x32_bf16(a, b[n], qa[n], 0, 0, 0);
        }
#pragma unroll
        for (int n = 0; n < 4; ++n) {
            int colc = w * 64 + n * 16 + lr;
            float bbq = bqk[colc];
#pragma unroll
            for (int r = 0; r < 4; ++r) {
                int row = lk * 4 + r;
                *(ushort*)(sB + swzb(row, colc * 2)) = f2bf(qa[n][r] + bbq);
            }
        }
    }
    __syncthreads();

    // ---- phase B: attention; wave w owns rows [w*4, w*4+4) ----
    {
        const int b0 = row0 + w * 4;
        int nodes[4], ptrs[4];
#pragma unroll
        for (int r = 0; r < 4; ++r) { nodes[r] = idx[b0 + r]; ptrs[r] = mptr[nodes[r]]; }

        for (int rr = 0; rr < 4; ++rr) {
            const int row = w * 4 + rr;
            const int b = b0 + rr;
            const int node = nodes[rr];
            const int ptr = ptrs[rr];
            ushort4 q4 = *(const ushort4*)(sB + swzb(row, l * 8));
            float q0 = bf2f(q4.x), q1 = bf2f(q4.y), q2 = bf2f(q4.z), q3 = bf2f(q4.w);
            const float* base = tm + (size_t)node * (NM * NF);
            const float* nfp = nf + (size_t)b * 256 + l * 4;

            float4 mem[NM];
            float sc[NM];
#pragma unroll
            for (int m = 0; m < NM; ++m) {
                float4 v = (m == ptr) ? *reinterpret_cast<const float4*>(nfp)
                                      : *reinterpret_cast<const float4*>(base + (size_t)m * 256 + l * 4);
                if (ptr > 0 && m == ptr - 1) { v.x *= DECAY; v.y *= DECAY; v.z *= DECAY; v.w *= DECAY; }
                mem[m] = v;
                sc[m] = q0 * v.x + q1 * v.y + q2 * v.z + q3 * v.w;
            }
#pragma unroll
            for (int m = 0; m < NM; ++m) {
                float s = sc[m];
#pragma unroll
                for (int d = 1; d < 64; d <<= 1) s += __shfl_xor(s, d, 64);
                sc[m] = s;
            }
            float mx = sc[0];
#pragma unroll
            for (int m = 1; m < NM; ++m) mx = fmaxf(mx, sc[m]);
            float e[NM], sum = 0.f;
#pragma unroll
            for (int m = 0; m < NM; ++m) { e[m] = __expf(sc[m] - mx); sum += e[m]; }
            float inv = 1.f / sum;
            float4 c = {0.f, 0.f, 0.f, 0.f};
#pragma unroll
            for (int m = 0; m < NM; ++m) {
                float wm = e[m] * inv;
                c.x += wm * mem[m].x; c.y += wm * mem[m].y; c.z += wm * mem[m].z; c.w += wm * mem[m].w;
            }
            ushort4 o;
            o.x = f2bf(c.x); o.y = f2bf(c.y); o.z = f2bf(c.z); o.w = f2bf(c.w);
            *(ushort4*)(sB + swzb(row, l * 8)) = o;
        }
    }
    __syncthreads();

    // ---- phase C: out = ctx @ Wv^T + bv ----
    f32x4 acc[4];
#pragma unroll
    for (int n = 0; n < 4; ++n) acc[n] = f32x4{0.f, 0.f, 0.f, 0.f};
    const ushort* vptr[4];
#pragma unroll
    for (int n = 0; n < 4; ++n) vptr[n] = Wvb + (size_t)(w * 64 + n * 16 + lr) * 256 + lk * 8;

#pragma unroll 2
    for (int k = 0; k < 256; k += 32) {
        bf16x8 a = *reinterpret_cast<const bf16x8*>(sB + swzb(lr, (k + lk * 8) * 2));
        bf16x8 b[4];
#pragma unroll
        for (int n = 0; n < 4; ++n) b[n] = *reinterpret_cast<const bf16x8*>(vptr[n] + k);
#pragma unroll
        for (int n = 0; n < 4; ++n)
            acc[n] = __builtin_amdgcn_mfma_f32_16x16x32_bf16(a, b[n], acc[n], 0, 0, 0);
    }
#pragma unroll
    for (int n = 0; n < 4; ++n) {
        int colc = w * 64 + n * 16 + lr;
        float bbv = bv[colc];
#pragma unroll
        for (int r = 0; r < 4; ++r) {
            int row = lk * 4 + r;
            out[(size_t)(row0 + row) * 256 + colc] = acc[n][r] + bbv;
        }
    }
}

// ---------------- launch ----------------
extern "C" void kernel_launch(void* const* d_in, const int* in_sizes, int n_in,
                              void* d_out, int out_size, void* d_ws, size_t ws_size,
                              hipStream_t stream) {
    const int*   node_indices = (const int*)  d_in[0];
    const float* node_feats   = (const float*)d_in[1];
    const float* hidden       = (const float*)d_in[2];
    const float* cell         = (const float*)d_in[3];
    const float* tmem         = (const float*)d_in[4];
    const int*   memory_ptr   = (const int*)  d_in[5];
    const float* W_ih         = (const float*)d_in[6];
    const float* W_hh         = (const float*)d_in[7];
    const float* b_ih         = (const float*)d_in[8];
    const float* b_hh         = (const float*)d_in[9];
    const float* Wq           = (const float*)d_in[10];
    const float* bq           = (const float*)d_in[11];
    const float* Wk           = (const float*)d_in[12];
    // d_in[13] = bk: softmax-invariant, unused
    const float* Wv           = (const float*)d_in[14];
    const float* bv           = (const float*)d_in[15];

    char* ws = (char*)d_ws;
    size_t off = 0;
    auto alloc = [&](size_t bytes) { char* p = ws + off; off += (bytes + 255) & ~(size_t)255; return p; };

    ushort* Wg    = (ushort*)alloc((size_t)1024 * 512 * 2);
    ushort* WqkT  = (ushort*)alloc((size_t)256 * 256 * 2);
    ushort* Wvb   = (ushort*)alloc((size_t)256 * 256 * 2);
    float*  bqk   = (float*) alloc((size_t)256 * 4);
    float*  bsum  = (float*) alloc((size_t)1024 * 4);
    ushort* Acat  = (ushort*)alloc((size_t)NB * 512 * 2);
    ushort* hnew  = (ushort*)alloc((size_t)NB * 256 * 2);

    k_prep<<<PB_TOT, 256, 0, stream>>>(W_ih, W_hh, b_ih, b_hh, Wq, bq, Wk, Wv,
                                       node_feats, hidden, node_indices,
                                       Wg, bsum, WqkT, bqk, Wvb, Acat);
    k_gates2<<<2048, 256, 0, stream>>>(Acat, Wg, bsum, node_indices, cell, hnew);
    k_attnout<<<NB / 16, 256, 0, stream>>>(hnew, WqkT, bqk, Wvb, bv, node_indices,
                                           memory_ptr, tmem, node_feats, (float*)d_out);
}

// Round 14
// 200.665 us; speedup vs baseline: 1.6528x; 1.0349x over previous
//
#include <hip/hip_runtime.h>
#include <hip/hip_bf16.h>

constexpr int NB = 32768;    // batch
constexpr int NF = 256;      // features
constexpr int NM = 10;       // memory slots
constexpr float DECAY = 0.9f;

using bf16x8 = __attribute__((ext_vector_type(8))) short;
using f32x4  = __attribute__((ext_vector_type(4))) float;

static __device__ __forceinline__ ushort f2bf(float x) {
    unsigned u = __float_as_uint(x);
    unsigned r = (u + 0x7fffu + ((u >> 16) & 1u)) >> 16;
    return (ushort)r;
}
static __device__ __forceinline__ float bf2f(ushort x) {
    return __uint_as_float(((unsigned)x) << 16);
}
static __device__ __forceinline__ float sigmoid_f(float x) {
    return 1.f / (1.f + __expf(-x));
}
static __device__ __forceinline__ float tanh_f(float x) {
    float e = __expf(2.f * x);
    return (e - 1.f) / (e + 1.f);
}
static __device__ __forceinline__ void gload16(const void* g, void* l) {
    __builtin_amdgcn_global_load_lds(
        (const __attribute__((address_space(1))) unsigned int*)g,
        (__attribute__((address_space(3))) unsigned int*)l, 16, 0, 0);
}
static __device__ __forceinline__ int swzb(int row, int byteInRow) {
    return (row * 512 + byteInRow) ^ ((row & 7) << 4);
}

// ---------------- fused weight/input prep (one launch) ----------------
constexpr int PB_ACAT = 16384;
constexpr int PB_WGI  = PB_ACAT + 1024;
constexpr int PB_WQKT = PB_WGI + 256;
constexpr int PB_WV   = PB_WQKT + 256;
constexpr int PB_TOT  = PB_WV + 1;

__global__ __launch_bounds__(256) void k_prep(
    const float* __restrict__ W_ih, const float* __restrict__ W_hh,
    const float* __restrict__ b_ih, const float* __restrict__ b_hh,
    const float* __restrict__ Wq, const float* __restrict__ bq,
    const float* __restrict__ Wk, const float* __restrict__ Wv,
    const float* __restrict__ nf, const float* __restrict__ hidden,
    const int* __restrict__ idx,
    ushort* __restrict__ Wg, float* __restrict__ bsum,
    ushort* __restrict__ WqkT, float* __restrict__ bqk,
    ushort* __restrict__ Wvb, ushort* __restrict__ Acat)
{
    const int blk = blockIdx.x, tid = threadIdx.x;
    if (blk < PB_ACAT) {
        int t = blk * 256 + tid;
        int row = t >> 7;
        int c4 = (t & 127) * 4;
        const float* src = (c4 < 256) ? (nf + (size_t)row * 256 + c4)
                                      : (hidden + (size_t)idx[row] * 256 + (c4 - 256));
        float4 v = *reinterpret_cast<const float4*>(src);
        ushort4 o;
        o.x = f2bf(v.x); o.y = f2bf(v.y); o.z = f2bf(v.z); o.w = f2bf(v.w);
        *reinterpret_cast<ushort4*>(Acat + (size_t)row * 512 + c4) = o;
    } else if (blk < PB_WGI) {
        int j = blk - PB_ACAT;
        for (int c = tid; c < 512; c += 256) {
            float v = (c < 256) ? W_ih[j * 256 + c] : W_hh[j * 256 + (c - 256)];
            Wg[j * 512 + c] = f2bf(v);
        }
        if (tid == 0) bsum[j] = b_ih[j] + b_hh[j];
    } else if (blk < PB_WQKT) {
        int i = blk - PB_WGI, a = tid;
        float s = 0.f;
#pragma unroll 8
        for (int j = 0; j < 256; ++j) s += Wq[j * 256 + a] * Wk[j * 256 + i];
        WqkT[i * 256 + a] = f2bf(s * 0.0625f);
    } else if (blk < PB_WV) {
        int t = (blk - PB_WQKT) * 256 + tid;
        Wvb[t] = f2bf(Wv[t]);
    } else {
        int i = tid;
        float s = 0.f;
#pragma unroll 8
        for (int j = 0; j < 256; ++j) s += bq[j] * Wk[j * 256 + i];
        bqk[i] = s * 0.0625f;
    }
}

// ---------------- gates GEMM: 512 threads, tile 128 rows x [64f x 4g], BK=64 ----------------
// Col-tile 256 -> Acat L3-refetch 4x (was 8x) and block count halves (1024): fewer
// barrier-drain events. Per-wave structure identical to the proven r13 kernel.
__global__ __launch_bounds__(512) void k_gates2(
    const ushort* __restrict__ Acat, const ushort* __restrict__ Wg,
    const float* __restrict__ bsum, const int* __restrict__ idx,
    const float* __restrict__ cell, ushort* __restrict__ h_new)
{
    __shared__ ushort As[2][128 * 32];   // 16 KB: half h holds K cols [k0+32h, +32)
    __shared__ ushort Bs[2][256 * 32];   // 32 KB: rows = g*64 + fi (gate g, feat fi in [0,64))
    const int t = threadIdx.x;
    const int w = t >> 6, l = t & 63;    // 8 waves
    const int wr = w >> 2, wc = w & 3;   // 2 x 4
    const int lr = l & 15, lk = l >> 4;

    // XCD-cohort remap: 4 feature-blocks (by) of one row-block share an XCD
    const int flat = blockIdx.x;         // [0, 1024)
    const int xc = flat & 7, grp = flat >> 3;
    const int by = grp & 3;
    const int bx = (grp >> 2) * 8 + xc;  // [0, 256)
    const int row0 = bx * 128;
    const int f0 = by * 64;              // feature block [f0, f0+64)

    f32x4 acc[4][4];                     // [m][gate]
#pragma unroll
    for (int m = 0; m < 4; ++m)
#pragma unroll
        for (int g = 0; g < 4; ++g) acc[m][g] = f32x4{0.f, 0.f, 0.f, 0.f};

    // staging: 48 chunks (2 halves x {8 A + 16 B}); wave w owns chunks w*6..w*6+5
    const int srow = l >> 2;
    const int scol = (l & 3) * 8;
    const ushort* src[6];
    ushort* dst[6];
#pragma unroll
    for (int j = 0; j < 6; ++j) {
        int q = w * 6 + j;
        int h = q / 24, c = q % 24;
        if (c < 8) {
            src[j] = Acat + (size_t)(row0 + c * 16 + srow) * 512 + h * 32 + scol;
            dst[j] = As[h] + c * 512;
        } else {
            int cb = c - 8;
            int g = cb >> 2, fi0 = (cb & 3) * 16;
            src[j] = Wg + (size_t)(g * 256 + f0 + fi0 + srow) * 512 + h * 32 + scol;
            dst[j] = Bs[h] + cb * 512;
        }
    }

    for (int k0 = 0; k0 < 512; k0 += 64) {
#pragma unroll
        for (int j = 0; j < 6; ++j) gload16(src[j] + k0, dst[j]);
        __syncthreads();
#pragma unroll
        for (int h = 0; h < 2; ++h) {
            bf16x8 af[4], bfr[4];
#pragma unroll
            for (int m = 0; m < 4; ++m)
                af[m] = *reinterpret_cast<const bf16x8*>(As[h] + (wr * 64 + m * 16 + lr) * 32 + lk * 8);
#pragma unroll
            for (int g = 0; g < 4; ++g)
                bfr[g] = *reinterpret_cast<const bf16x8*>(Bs[h] + (g * 64 + wc * 16 + lr) * 32 + lk * 8);
#pragma unroll
            for (int m = 0; m < 4; ++m)
#pragma unroll
                for (int g = 0; g < 4; ++g)
                    acc[m][g] = __builtin_amdgcn_mfma_f32_16x16x32_bf16(af[m], bfr[g], acc[m][g], 0, 0, 0);
        }
        __syncthreads();
    }

    // ---- epilogue: per lane, feature f fixed; all 4 gates local ----
    const int f = f0 + wc * 16 + lr;
    float bs[4];
#pragma unroll
    for (int g = 0; g < 4; ++g) bs[g] = bsum[g * 256 + f];

    int nodev[4][4];
#pragma unroll
    for (int m = 0; m < 4; ++m)
#pragma unroll
        for (int r = 0; r < 4; ++r)
            nodev[m][r] = idx[row0 + wr * 64 + m * 16 + lk * 4 + r];

#pragma unroll
    for (int m = 0; m < 4; ++m) {
#pragma unroll
        for (int r = 0; r < 4; ++r) {
            float gi = acc[m][0][r] + bs[0];
            float gf = acc[m][1][r] + bs[1];
            float gg = acc[m][2][r] + bs[2];
            float go = acc[m][3][r] + bs[3];
            float cp = cell[(size_t)nodev[m][r] * 256 + f];
            float cn = sigmoid_f(gf) * cp + sigmoid_f(gi) * tanh_f(gg);
            float hn = sigmoid_f(go) * tanh_f(cn);
            int row = row0 + wr * 64 + m * 16 + lk * 4 + r;
            h_new[(size_t)row * 256 + f] = f2bf(hn);
        }
    }
}

// ---------------- fused tail: q-GEMM -> attention -> out-GEMM (r13 form) ----------------
__global__ __launch_bounds__(256) void k_attnout(
    const ushort* __restrict__ hnew, const ushort* __restrict__ WqkT,
    const float* __restrict__ bqk, const ushort* __restrict__ Wvb,
    const float* __restrict__ bv, const int* __restrict__ idx,
    const int* __restrict__ mptr, const float* __restrict__ tm,
    const float* __restrict__ nf, float* __restrict__ out)
{
    __shared__ ushort sC[16 * 256];     // 8 KB; q rows, then (in-place) ctx rows
    char* sB = (char*)sC;
    const int t = threadIdx.x, w = t >> 6, l = t & 63;
    const int lr = l & 15, lk = l >> 4;
    const int row0 = blockIdx.x * 16;

    // ---- phase A: q = hnew[16x256] @ WqkT^T + bqk -> LDS (swizzled bf16) ----
    {
        f32x4 qa[4];
#pragma unroll
        for (int n = 0; n < 4; ++n) qa[n] = f32x4{0.f, 0.f, 0.f, 0.f};
        const ushort* ap = hnew + (size_t)(row0 + lr) * 256 + lk * 8;
        const ushort* bp[4];
#pragma unroll
        for (int n = 0; n < 4; ++n) bp[n] = WqkT + (size_t)(w * 64 + n * 16 + lr) * 256 + lk * 8;
#pragma unroll 2
        for (int k0 = 0; k0 < 256; k0 += 32) {
            bf16x8 a = *reinterpret_cast<const bf16x8*>(ap + k0);
            bf16x8 b[4];
#pragma unroll
            for (int n = 0; n < 4; ++n) b[n] = *reinterpret_cast<const bf16x8*>(bp[n] + k0);
#pragma unroll
            for (int n = 0; n < 4; ++n)
                qa[n] = __builtin_amdgcn_mfma_f32_16x16x32_bf16(a, b[n], qa[n], 0, 0, 0);
        }
#pragma unroll
        for (int n = 0; n < 4; ++n) {
            int colc = w * 64 + n * 16 + lr;
            float bbq = bqk[colc];
#pragma unroll
            for (int r = 0; r < 4; ++r) {
                int row = lk * 4 + r;
                *(ushort*)(sB + swzb(row, colc * 2)) = f2bf(qa[n][r] + bbq);
            }
        }
    }
    __syncthreads();

    // ---- phase B: attention; wave w owns rows [w*4, w*4+4) ----
    {
        const int b0 = row0 + w * 4;
        int nodes[4], ptrs[4];
#pragma unroll
        for (int r = 0; r < 4; ++r) { nodes[r] = idx[b0 + r]; ptrs[r] = mptr[nodes[r]]; }

        for (int rr = 0; rr < 4; ++rr) {
            const int row = w * 4 + rr;
            const int b = b0 + rr;
            const int node = nodes[rr];
            const int ptr = ptrs[rr];
            ushort4 q4 = *(const ushort4*)(sB + swzb(row, l * 8));
            float q0 = bf2f(q4.x), q1 = bf2f(q4.y), q2 = bf2f(q4.z), q3 = bf2f(q4.w);
            const float* base = tm + (size_t)node * (NM * NF);
            const float* nfp = nf + (size_t)b * 256 + l * 4;

            float4 mem[NM];
            float sc[NM];
#pragma unroll
            for (int m = 0; m < NM; ++m) {
                float4 v = (m == ptr) ? *reinterpret_cast<const float4*>(nfp)
                                      : *reinterpret_cast<const float4*>(base + (size_t)m * 256 + l * 4);
                if (ptr > 0 && m == ptr - 1) { v.x *= DECAY; v.y *= DECAY; v.z *= DECAY; v.w *= DECAY; }
                mem[m] = v;
                sc[m] = q0 * v.x + q1 * v.y + q2 * v.z + q3 * v.w;
            }
#pragma unroll
            for (int m = 0; m < NM; ++m) {
                float s = sc[m];
#pragma unroll
                for (int d = 1; d < 64; d <<= 1) s += __shfl_xor(s, d, 64);
                sc[m] = s;
            }
            float mx = sc[0];
#pragma unroll
            for (int m = 1; m < NM; ++m) mx = fmaxf(mx, sc[m]);
            float e[NM], sum = 0.f;
#pragma unroll
            for (int m = 0; m < NM; ++m) { e[m] = __expf(sc[m] - mx); sum += e[m]; }
            float inv = 1.f / sum;
            float4 c = {0.f, 0.f, 0.f, 0.f};
#pragma unroll
            for (int m = 0; m < NM; ++m) {
                float wm = e[m] * inv;
                c.x += wm * mem[m].x; c.y += wm * mem[m].y; c.z += wm * mem[m].z; c.w += wm * mem[m].w;
            }
            ushort4 o;
            o.x = f2bf(c.x); o.y = f2bf(c.y); o.z = f2bf(c.z); o.w = f2bf(c.w);
            *(ushort4*)(sB + swzb(row, l * 8)) = o;
        }
    }
    __syncthreads();

    // ---- phase C: out = ctx @ Wv^T + bv ----
    f32x4 acc[4];
#pragma unroll
    for (int n = 0; n < 4; ++n) acc[n] = f32x4{0.f, 0.f, 0.f, 0.f};
    const ushort* vptr[4];
#pragma unroll
    for (int n = 0; n < 4; ++n) vptr[n] = Wvb + (size_t)(w * 64 + n * 16 + lr) * 256 + lk * 8;

#pragma unroll 2
    for (int k = 0; k < 256; k += 32) {
        bf16x8 a = *reinterpret_cast<const bf16x8*>(sB + swzb(lr, (k + lk * 8) * 2));
        bf16x8 b[4];
#pragma unroll
        for (int n = 0; n < 4; ++n) b[n] = *reinterpret_cast<const bf16x8*>(vptr[n] + k);
#pragma unroll
        for (int n = 0; n < 4; ++n)
            acc[n] = __builtin_amdgcn_mfma_f32_16x16x32_bf16(a, b[n], acc[n], 0, 0, 0);
    }
#pragma unroll
    for (int n = 0; n < 4; ++n) {
        int colc = w * 64 + n * 16 + lr;
        float bbv = bv[colc];
#pragma unroll
        for (int r = 0; r < 4; ++r) {
            int row = lk * 4 + r;
            out[(size_t)(row0 + row) * 256 + colc] = acc[n][r] + bbv;
        }
    }
}

// ---------------- launch ----------------
extern "C" void kernel_launch(void* const* d_in, const int* in_sizes, int n_in,
                              void* d_out, int out_size, void* d_ws, size_t ws_size,
                              hipStream_t stream) {
    const int*   node_indices = (const int*)  d_in[0];
    const float* node_feats   = (const float*)d_in[1];
    const float* hidden       = (const float*)d_in[2];
    const float* cell         = (const float*)d_in[3];
    const float* tmem         = (const float*)d_in[4];
    const int*   memory_ptr   = (const int*)  d_in[5];
    const float* W_ih         = (const float*)d_in[6];
    const float* W_hh         = (const float*)d_in[7];
    const float* b_ih         = (const float*)d_in[8];
    const float* b_hh         = (const float*)d_in[9];
    const float* Wq           = (const float*)d_in[10];
    const float* bq           = (const float*)d_in[11];
    const float* Wk           = (const float*)d_in[12];
    // d_in[13] = bk: softmax-invariant, unused
    const float* Wv           = (const float*)d_in[14];
    const float* bv           = (const float*)d_in[15];

    char* ws = (char*)d_ws;
    size_t off = 0;
    auto alloc = [&](size_t bytes) { char* p = ws + off; off += (bytes + 255) & ~(size_t)255; return p; };

    ushort* Wg    = (ushort*)alloc((size_t)1024 * 512 * 2);
    ushort* WqkT  = (ushort*)alloc((size_t)256 * 256 * 2);
    ushort* Wvb   = (ushort*)alloc((size_t)256 * 256 * 2);
    float*  bqk   = (float*) alloc((size_t)256 * 4);
    float*  bsum  = (float*) alloc((size_t)1024 * 4);
    ushort* Acat  = (ushort*)alloc((size_t)NB * 512 * 2);
    ushort* hnew  = (ushort*)alloc((size_t)NB * 256 * 2);

    k_prep<<<PB_TOT, 256, 0, stream>>>(W_ih, W_hh, b_ih, b_hh, Wq, bq, Wk, Wv,
                                       node_feats, hidden, node_indices,
                                       Wg, bsum, WqkT, bqk, Wvb, Acat);
    k_gates2<<<1024, 512, 0, stream>>>(Acat, Wg, bsum, node_indices, cell, hnew);
    k_attnout<<<NB / 16, 256, 0, stream>>>(hnew, WqkT, bqk, Wvb, bv, node_indices,
                                           memory_ptr, tmem, node_feats, (float*)d_out);
}